// Round 11
// baseline (380.374 us; speedup 1.0000x reference)
//
#include <hip/hip_runtime.h>
#include <hip/hip_bf16.h>

// ChebyKAN: y[b,o] = sum_{i,d} T_d(tanh(x[b,i])) * W[i,o,d]
// GEMM M=16384, N=1024, K=9216 with generated A (packed-fp16 Chebyshev recurrence).
// R8: block tile 256x128 (4 waves of 64m x 128n, grid 512 = 2 blocks/CU exact).
//     Halves per-block LDS-read traffic per MFMA (DS pipe was top consumer at
//     ~58% of cycles): B-reads stay 8/deg/wave, MFMA doubles to 16/deg/wave.
//     launch_bounds (256,1): acc 128 AGPR + ~160 VGPR = ~288 unified > 256.
//     Waits re-derived for loadx=8: q0=14, q1=6, q2=14. Same R5 wt layout.

#define WSCALE 4096.0f
#define INV_WSCALE (1.0f/4096.0f)

typedef _Float16 f16;
typedef __fp16   hf2  __attribute__((ext_vector_type(2)));
typedef _Float16 f16x8 __attribute__((ext_vector_type(8)));
typedef float    f32x4 __attribute__((ext_vector_type(4)));
typedef float    f32x16 __attribute__((ext_vector_type(16)));

union F16x8u { hf2 h2[4]; f16x8 v8; };

// ---- kernel 1: repack cc [I][O][9] f32 -> wt, 16B-chunk-permuted so the
// GEMM's linear global_load_lds produces the conflict-free LDS layout (R5).
__global__ __launch_bounds__(256) void wt_transform(const float* __restrict__ cc,
                                                    f16* __restrict__ wt) {
  int t    = blockIdx.x * 256 + threadIdx.x;   // 294912 threads
  int j4   = t & 127;
  int grp  = t >> 7;
  int ncol = grp & 7;
  int rest = grp >> 3;
  int ic   = rest & 31;
  int d    = rest >> 5;                        // 0..8
  int u    = j4 >> 5;
  int h    = (j4 >> 4) & 1;
  int r    = j4 & 15;
  int rk   = (r >> 1) & 3;
  size_t base = (size_t)(d * 32 + ic) * 32768 + (size_t)ncol * 4096 + (size_t)j4 * 32;
#pragma unroll
  for (int v = 0; v < 4; ++v) {
    int tt = v ^ rk;
    int q  = tt & 1, kl = tt >> 1;
    int o  = ncol * 128 + u * 32 + q * 16 + r;
    int ib = ic * 32 + h * 16 + kl * 8;
    f16x8 val;
#pragma unroll
    for (int e = 0; e < 8; ++e)
      val[e] = (f16)(cc[((size_t)(ib + e) * 1024 + o) * 9 + d] * WSCALE);
    *(f16x8*)(wt + base + v * 8) = val;
  }
}

// ---- kernel 2: fused basis-gen + GEMM, 256x128 tile, 4 waves of 64m x 128n
__global__ __launch_bounds__(256, 1) void cheby_gemm(const float* __restrict__ x,
                                                     const f16* __restrict__ wt,
                                                     float* __restrict__ out) {
  __shared__ f16 bbuf[9][4096];               // buffer per degree: 9 x 8KB = 72KB

  const int tid  = threadIdx.x;
  const int wid  = tid >> 6;                  // wave id = m-stripe 0..3 (64 rows each)
  const int lane = tid & 63;
  const int lr   = lane & 31;                 // m-row within 32-block / B col within 32
  const int lh   = lane >> 5;                 // k-subgroup select
  const int mrow = blockIdx.x >> 3;           // 0..63
  const int ncol = blockIdx.x & 7;            // round-robin XCD: wt slice L2-resident
  const int m0   = mrow * 256 + wid * 64;
  const int n0   = ncol * 128;
  const int nc128 = ncol * 128;
  // R2-pattern conflict-free lane term (f16 units), nb/h become imm offsets:
  const int rbase = ((lane & 15) * 4 + ((lane >> 4) ^ ((lane >> 1) & 3))) * 8;

  auto stage = [&](int cn, int dn, int buf) {
    const f16* src = wt + ((size_t)(dn * 32 + cn) * 1024 + nc128) * 32;
    __builtin_amdgcn_global_load_lds(
        (const __attribute__((address_space(1))) unsigned*)(src + tid * 8),
        (__attribute__((address_space(3))) unsigned*)(&bbuf[buf][wid * 512]),
        16, 0, 0);
    __builtin_amdgcn_global_load_lds(
        (const __attribute__((address_space(1))) unsigned*)(src + 2048 + tid * 8),
        (__attribute__((address_space(3))) unsigned*)(&bbuf[buf][wid * 512 + 2048]),
        16, 0, 0);
  };
  auto stage3 = [&](int cn, int dn0, int b0) {
    stage(cn, dn0, b0); stage(cn, dn0 + 1, b0 + 1); stage(cn, dn0 + 2, b0 + 2);
  };

  f32x16 acc[2][4];                           // [mb][nb]
#pragma unroll
  for (int a = 0; a < 2; ++a)
#pragma unroll
    for (int b = 0; b < 4; ++b)
#pragma unroll
      for (int j = 0; j < 16; ++j) acc[a][b][j] = 0.f;

  const f16x8 ones  = {(f16)1,(f16)1,(f16)1,(f16)1,(f16)1,(f16)1,(f16)1,(f16)1};
  const f16x8 half8 = {(f16)0.5f,(f16)0.5f,(f16)0.5f,(f16)0.5f,
                       (f16)0.5f,(f16)0.5f,(f16)0.5f,(f16)0.5f};
  f16x8 Tm1[2][2], Tm2[2][2], t2v[2][2], t2n[2][2];   // [mb][h]
  f32x4 xf[2][2][2];                                   // [mb][h][half]

  auto loadx = [&](int cn) {   // 8 VMEM instrs
#pragma unroll
    for (int mb = 0; mb < 2; ++mb)
#pragma unroll
      for (int h = 0; h < 2; ++h) {
        const float* p = x + (size_t)(m0 + mb * 32 + lr) * 1024 + cn * 32 + h * 16 + lh * 8;
        xf[mb][h][0] = *(const f32x4*)p;
        xf[mb][h][1] = *(const f32x4*)(p + 4);
      }
  };
  auto dotanh = [&]() {        // xf -> t2n = 2*tanh(x) (f16 via cvt_pkrtz)
#pragma unroll
    for (int mb = 0; mb < 2; ++mb)
#pragma unroll
      for (int h = 0; h < 2; ++h) {
        float tf[8];
#pragma unroll
        for (int e = 0; e < 8; ++e) {
          float xx = (e < 4) ? xf[mb][h][0][e] : xf[mb][h][1][e - 4];
          tf[e] = 1.f - 2.f * __builtin_amdgcn_rcpf(__expf(2.f * xx) + 1.f);
        }
        F16x8u u;
#pragma unroll
        for (int p = 0; p < 4; ++p)
          u.h2[p] = __builtin_amdgcn_cvt_pkrtz(tf[2 * p], tf[2 * p + 1]);
        t2n[mb][h] = u.v8 + u.v8;   // exact x2
      }
  };

// rec: DST = t2v * S1 - S2 (packed f16), over [2][2] frags
#define REC(DST, S1, S2)                                                       \
  _Pragma("unroll") for (int mb = 0; mb < 2; ++mb)                             \
    _Pragma("unroll") for (int h = 0; h < 2; ++h)                              \
      DST[mb][h] = __builtin_elementwise_fma(t2v[mb][h], S1[mb][h], -S2[mb][h]);

// cluster: read 8 B frags from bbuf[D] (imm offsets), 16 MFMAs with AF
#define CLUSTER(AF, D)                                                         \
  {                                                                            \
    const f16* bb = &bbuf[(D)][0];                                             \
    f16x8 bf[4][2];                                                            \
    _Pragma("unroll") for (int nb = 0; nb < 4; ++nb)                           \
      _Pragma("unroll") for (int h = 0; h < 2; ++h)                            \
        bf[nb][h] = *(const f16x8*)&bb[rbase + nb * 1024 + h * 512];           \
    _Pragma("unroll") for (int nb = 0; nb < 4; ++nb)                           \
      _Pragma("unroll") for (int mb = 0; mb < 2; ++mb) {                       \
        acc[mb][nb] = __builtin_amdgcn_mfma_f32_32x32x16_f16(AF[mb][0], bf[nb][0], \
                                                             acc[mb][nb], 0, 0, 0); \
        acc[mb][nb] = __builtin_amdgcn_mfma_f32_32x32x16_f16(AF[mb][1], bf[nb][1], \
                                                             acc[mb][nb], 0, 0, 0); \
      }                                                                        \
  }

  // prologue: stage chunk0 deg 0-2 + deg 3-5, load+tanh chunk0 x
  stage3(0, 0, 0);
  stage3(0, 3, 3);
  loadx(0);
  dotanh();

  f16x8 onesA[2][2], A1[2][2], A2[2][2];
#pragma unroll
  for (int mb = 0; mb < 2; ++mb)
#pragma unroll
    for (int h = 0; h < 2; ++h) onesA[mb][h] = ones;

  for (int c = 0; c < 32; ++c) {
    const bool lastc = (c == 31);

    // ---- phase q0: degrees 0,1,2 (bufs 0-2; staged at q1 of c-1)
    // after stage3(c,0-2): loadx(c)[8] + stage3(c,3-5)[6] -> vmcnt(14)
    asm volatile("s_waitcnt vmcnt(14)" ::: "memory");
    __builtin_amdgcn_s_barrier();
    stage3(c, 6, 6);                        // deg 6-8 chunk c -> bufs 6-8
#pragma unroll
    for (int mb = 0; mb < 2; ++mb)
#pragma unroll
      for (int h = 0; h < 2; ++h) {
        t2v[mb][h] = t2n[mb][h];            // adopt chunk c tanh
        A1[mb][h]  = t2v[mb][h] * half8;    // T1 = t (exact)
      }
    REC(A2, A1, onesA)                      // T2 = 2t*T1 - 1
    CLUSTER(onesA, 0)
    CLUSTER(A1, 1)
    CLUSTER(A2, 2)
#pragma unroll
    for (int mb = 0; mb < 2; ++mb)
#pragma unroll
      for (int h = 0; h < 2; ++h) { Tm1[mb][h] = A2[mb][h]; Tm2[mb][h] = A1[mb][h]; }

    // ---- phase q1: degrees 3,4,5 (bufs 3-5; staged at q2 of c-1)
    // after stage3(c,3-5): stage3(c,6-8)[6] -> vmcnt(6)
    asm volatile("s_waitcnt vmcnt(6)" ::: "memory");
    __builtin_amdgcn_s_barrier();
    if (!lastc) {
      stage3(c + 1, 0, 0);                  // deg 0-2 chunk c+1 -> bufs 0-2
      loadx(c + 1);                         // 8 VMEM, tanh'd at q2
    }
    {
      f16x8 A3[2][2], A4[2][2], A5[2][2];
      REC(A3, Tm1, Tm2)
      REC(A4, A3, Tm1)
      REC(A5, A4, A3)
      CLUSTER(A3, 3)
      CLUSTER(A4, 4)
      CLUSTER(A5, 5)
#pragma unroll
      for (int mb = 0; mb < 2; ++mb)
#pragma unroll
        for (int h = 0; h < 2; ++h) { Tm1[mb][h] = A5[mb][h]; Tm2[mb][h] = A4[mb][h]; }
    }

    // ---- phase q2: degrees 6,7,8 (bufs 6-8; staged at q0 of c)
    // after stage3(c,6-8): stage3(c+1,0-2)[6] + loadx(c+1)[8] -> vmcnt(14)
    if (lastc) asm volatile("s_waitcnt vmcnt(0)" ::: "memory");
    else       asm volatile("s_waitcnt vmcnt(14)" ::: "memory");
    __builtin_amdgcn_s_barrier();
    if (!lastc) {
      stage3(c + 1, 3, 3);                  // deg 3-5 chunk c+1 -> bufs 3-5
      dotanh();                             // chunk c+1 seed (overlappable VALU)
    }
    {
      f16x8 A6[2][2], A7[2][2], A8[2][2];
      REC(A6, Tm1, Tm2)
      REC(A7, A6, Tm1)
      REC(A8, A7, A6)
      CLUSTER(A6, 6)
      CLUSTER(A7, 7)
      CLUSTER(A8, 8)
    }
  }
#undef REC
#undef CLUSTER

  // epilogue: 32x32 C/D map: col = lane&31, row = (j&3) + 8*(j>>2) + 4*(lane>>5)
#pragma unroll
  for (int mb = 0; mb < 2; ++mb)
#pragma unroll
    for (int nb = 0; nb < 4; ++nb)
#pragma unroll
      for (int j = 0; j < 16; ++j) {
        int row = m0 + mb * 32 + 4 * lh + (j & 3) + 8 * (j >> 2);
        int col = n0 + nb * 32 + lr;
        out[(size_t)row * 1024 + col] = acc[mb][nb][j] * INV_WSCALE;
      }
}

extern "C" void kernel_launch(void* const* d_in, const int* in_sizes, int n_in,
                              void* d_out, int out_size, void* d_ws, size_t ws_size,
                              hipStream_t stream) {
  const float* x  = (const float*)d_in[0];
  const float* cc = (const float*)d_in[1];
  f16*   wt  = (f16*)d_ws;                // 9*32*1024*32*2 = 18,874,368 B
  float* out = (float*)d_out;

  hipLaunchKernelGGL(wt_transform, dim3(1152), dim3(256), 0, stream, cc, wt);
  hipLaunchKernelGGL(cheby_gemm, dim3(512), dim3(256), 0, stream, x, wt, out);
}

// Round 12
// 366.154 us; speedup vs baseline: 1.0388x; 1.0388x over previous
//
#include <hip/hip_runtime.h>
#include <hip/hip_bf16.h>

// ChebyKAN: y[b,o] = sum_{i,d} T_d(tanh(x[b,i])) * W[i,o,d]
// GEMM M=16384, N=1024, K=9216 with generated A (packed-fp16 Chebyshev recurrence).
// R9: one barrier + one counted vmcnt per CHUNK (9 degrees) instead of per
//     3-degree phase: 512-thr block (8 waves, 2/SIMD), 256x128 tile, wave
//     64x64 (4m x 2n), 18 LDS degree-buffers (two 9-buf sets, 144KB) swapped
//     by chunk parity. 72 MFMA per wave per barrier-free window -> waves
//     drift, pipes (MFMA/DS/VALU) overlap instead of lockstep-bursting.
//     Same R5 conflict-free wt layout; stage = 1 gload_lds instr per 8KB buf.

#define WSCALE 4096.0f
#define INV_WSCALE (1.0f/4096.0f)

typedef _Float16 f16;
typedef __fp16   hf2  __attribute__((ext_vector_type(2)));
typedef _Float16 f16x8 __attribute__((ext_vector_type(8)));
typedef float    f32x4 __attribute__((ext_vector_type(4)));
typedef float    f32x16 __attribute__((ext_vector_type(16)));

union F16x8u { hf2 h2[4]; f16x8 v8; };

// ---- kernel 1: repack cc [I][O][9] f32 -> wt, 16B-chunk-permuted so the
// GEMM's linear global_load_lds produces the conflict-free LDS layout (R5).
__global__ __launch_bounds__(256) void wt_transform(const float* __restrict__ cc,
                                                    f16* __restrict__ wt) {
  int t    = blockIdx.x * 256 + threadIdx.x;   // 294912 threads
  int j4   = t & 127;
  int grp  = t >> 7;
  int ncol = grp & 7;
  int rest = grp >> 3;
  int ic   = rest & 31;
  int d    = rest >> 5;                        // 0..8
  int u    = j4 >> 5;
  int h    = (j4 >> 4) & 1;
  int r    = j4 & 15;
  int rk   = (r >> 1) & 3;
  size_t base = (size_t)(d * 32 + ic) * 32768 + (size_t)ncol * 4096 + (size_t)j4 * 32;
#pragma unroll
  for (int v = 0; v < 4; ++v) {
    int tt = v ^ rk;
    int q  = tt & 1, kl = tt >> 1;
    int o  = ncol * 128 + u * 32 + q * 16 + r;
    int ib = ic * 32 + h * 16 + kl * 8;
    f16x8 val;
#pragma unroll
    for (int e = 0; e < 8; ++e)
      val[e] = (f16)(cc[((size_t)(ib + e) * 1024 + o) * 9 + d] * WSCALE);
    *(f16x8*)(wt + base + v * 8) = val;
  }
}

// ---- kernel 2: fused basis-gen + GEMM, 256x128 tile, 8 waves of 64m x 64n
__global__ __launch_bounds__(512, 2) void cheby_gemm(const float* __restrict__ x,
                                                     const f16* __restrict__ wt,
                                                     float* __restrict__ out) {
  __shared__ f16 bbuf[18][4096];              // 2 sets x 9 degree-bufs x 8KB = 144KB

  const int tid  = threadIdx.x;
  const int wid  = tid >> 6;                  // 0..7
  const int lane = tid & 63;
  const int lr   = lane & 31;
  const int lh   = lane >> 5;
  const int wm   = wid >> 1;                  // m-quarter 0..3
  const int wn   = wid & 1;                   // n-half 0..1
  const int mrow = blockIdx.x >> 3;           // 0..63
  const int ncol = blockIdx.x & 7;            // round-robin XCD: wt slice L2-resident
  const int m0   = mrow * 256 + wm * 64;
  const int n0   = ncol * 128 + wn * 64;
  // R2-pattern conflict-free lane term + wave n-half fold (f16 units):
  const int rbase = wn * 2048 + ((lane & 15) * 4 + ((lane >> 4) ^ ((lane >> 1) & 3))) * 8;

  // stage one 8KB degree-buf with a single global_load_lds (512 thr x 16B)
  auto stage = [&](int cn, int dn, int buf) {
    const f16* src = wt + (size_t)(dn * 32 + cn) * 32768 + (size_t)ncol * 4096;
    __builtin_amdgcn_global_load_lds(
        (const __attribute__((address_space(1))) unsigned*)(src + tid * 8),
        (__attribute__((address_space(3))) unsigned*)(&bbuf[buf][wid * 512]),
        16, 0, 0);
  };
  auto stage9 = [&](int cn, int b0) {
#pragma unroll
    for (int d = 0; d < 9; ++d) stage(cn, d, b0 + d);
  };

  f32x16 acc[2][2];                           // [mb][nb]
#pragma unroll
  for (int a = 0; a < 2; ++a)
#pragma unroll
    for (int b = 0; b < 2; ++b)
#pragma unroll
      for (int j = 0; j < 16; ++j) acc[a][b][j] = 0.f;

  const f16x8 ones  = {(f16)1,(f16)1,(f16)1,(f16)1,(f16)1,(f16)1,(f16)1,(f16)1};
  const f16x8 half8 = {(f16)0.5f,(f16)0.5f,(f16)0.5f,(f16)0.5f,
                       (f16)0.5f,(f16)0.5f,(f16)0.5f,(f16)0.5f};
  f16x8 t2v[2][2], t2n[2][2];                 // [mb][h]
  f32x4 xf[2][2][2];                          // [mb][h][half]

  auto loadx = [&](int cn) {   // 8 VMEM instrs
#pragma unroll
    for (int mb = 0; mb < 2; ++mb)
#pragma unroll
      for (int h = 0; h < 2; ++h) {
        const float* p = x + (size_t)(m0 + mb * 32 + lr) * 1024 + cn * 32 + h * 16 + lh * 8;
        xf[mb][h][0] = *(const f32x4*)p;
        xf[mb][h][1] = *(const f32x4*)(p + 4);
      }
  };
  auto dotanh = [&]() {        // xf -> t2n = 2*tanh(x) (f16 via cvt_pkrtz)
#pragma unroll
    for (int mb = 0; mb < 2; ++mb)
#pragma unroll
      for (int h = 0; h < 2; ++h) {
        float tf[8];
#pragma unroll
        for (int e = 0; e < 8; ++e) {
          float xx = (e < 4) ? xf[mb][h][0][e] : xf[mb][h][1][e - 4];
          tf[e] = 1.f - 2.f * __builtin_amdgcn_rcpf(__expf(2.f * xx) + 1.f);
        }
        F16x8u u;
#pragma unroll
        for (int p = 0; p < 4; ++p)
          u.h2[p] = __builtin_amdgcn_cvt_pkrtz(tf[2 * p], tf[2 * p + 1]);
        t2n[mb][h] = u.v8 + u.v8;   // exact x2
      }
  };

// rec: DST = t2v * S1 - S2 (packed f16), over [2][2] frags
#define REC(DST, S1, S2)                                                       \
  _Pragma("unroll") for (int mb = 0; mb < 2; ++mb)                             \
    _Pragma("unroll") for (int h = 0; h < 2; ++h)                              \
      DST[mb][h] = __builtin_elementwise_fma(t2v[mb][h], S1[mb][h], -S2[mb][h]);

// cluster: 4 B-frag reads from bb + s-degree offset (imm nb/h offs), 8 MFMAs
#define CLUSTER(AF, DIDX)                                                      \
  {                                                                            \
    const f16* bb = &bbuf[0][0] + sbase + (DIDX) * 4096 + rbase;               \
    f16x8 bf[2][2];                                                            \
    _Pragma("unroll") for (int nb = 0; nb < 2; ++nb)                           \
      _Pragma("unroll") for (int h = 0; h < 2; ++h)                            \
        bf[nb][h] = *(const f16x8*)&bb[nb * 1024 + h * 512];                   \
    _Pragma("unroll") for (int nb = 0; nb < 2; ++nb)                           \
      _Pragma("unroll") for (int mb = 0; mb < 2; ++mb) {                       \
        acc[mb][nb] = __builtin_amdgcn_mfma_f32_32x32x16_f16(AF[mb][0], bf[nb][0], \
                                                             acc[mb][nb], 0, 0, 0); \
        acc[mb][nb] = __builtin_amdgcn_mfma_f32_32x32x16_f16(AF[mb][1], bf[nb][1], \
                                                             acc[mb][nb], 0, 0, 0); \
      }                                                                        \
  }

  // prologue: stage chunk0 set0, load+tanh chunk0 x (compiler drains prologue)
  stage9(0, 0);
  loadx(0);
  dotanh();

  f16x8 onesA[2][2];
#pragma unroll
  for (int mb = 0; mb < 2; ++mb)
#pragma unroll
    for (int h = 0; h < 2; ++h) onesA[mb][h] = ones;

  for (int c = 0; c < 32; ++c) {
    const bool lastc = (c == 31);
    const int  sbase = (c & 1) * 9 * 4096;    // this chunk's buf set (f16 units)
    const int  nbase = (1 - (c & 1)) * 9;     // next chunk's buf set index

    // prove own stage9(c) retired: after it only loadx(c) [8] was issued.
    asm volatile("s_waitcnt vmcnt(8)" ::: "memory");
    __builtin_amdgcn_s_barrier();
    if (!lastc) {
      stage9(c + 1, nbase);                   // 9 VMEM -> other set
      loadx(c + 1);                           // 8 VMEM
    }

    // 9 degrees, rolling recurrence; full barrier-free DAG
    f16x8 A1[2][2], A2[2][2], A3[2][2], A4[2][2], A5[2][2], A6[2][2], A7[2][2], A8[2][2];
#pragma unroll
    for (int mb = 0; mb < 2; ++mb)
#pragma unroll
      for (int h = 0; h < 2; ++h) {
        t2v[mb][h] = t2n[mb][h];              // adopt chunk c tanh
        A1[mb][h]  = t2v[mb][h] * half8;      // T1 = t (exact)
      }
    CLUSTER(onesA, 0)
    CLUSTER(A1, 1)
    REC(A2, A1, onesA)  CLUSTER(A2, 2)
    REC(A3, A2, A1)     CLUSTER(A3, 3)
    REC(A4, A3, A2)     CLUSTER(A4, 4)
    REC(A5, A4, A3)     CLUSTER(A5, 5)
    REC(A6, A5, A4)     CLUSTER(A6, 6)
    REC(A7, A6, A5)     CLUSTER(A7, 7)
    REC(A8, A7, A6)     CLUSTER(A8, 8)

    if (!lastc) dotanh();                     // chunk c+1 seed (textually last)
  }
#undef REC
#undef CLUSTER

  // epilogue: 32x32 C/D map: col = lane&31, row = (j&3) + 8*(j>>2) + 4*(lane>>5)
#pragma unroll
  for (int mb = 0; mb < 2; ++mb)
#pragma unroll
    for (int nb = 0; nb < 2; ++nb)
#pragma unroll
      for (int j = 0; j < 16; ++j) {
        int row = m0 + mb * 32 + 4 * lh + (j & 3) + 8 * (j >> 2);
        int col = n0 + nb * 32 + lr;
        out[(size_t)row * 1024 + col] = acc[mb][nb][j] * INV_WSCALE;
      }
}

extern "C" void kernel_launch(void* const* d_in, const int* in_sizes, int n_in,
                              void* d_out, int out_size, void* d_ws, size_t ws_size,
                              hipStream_t stream) {
  const float* x  = (const float*)d_in[0];
  const float* cc = (const float*)d_in[1];
  f16*   wt  = (f16*)d_ws;                // 9*32*1024*32*2 = 18,874,368 B
  float* out = (float*)d_out;

  hipLaunchKernelGGL(wt_transform, dim3(1152), dim3(256), 0, stream, cc, wt);
  hipLaunchKernelGGL(cheby_gemm, dim3(512), dim3(512), 0, stream, x, wt, out);
}